// Round 4
// baseline (133.052 us; speedup 1.0000x reference)
//
#include <hip/hip_runtime.h>
#include <stdint.h>

#define NROWS 8192
#define DD 128
#define EPS 1e-8f
#define LOG2E 1.4426950408889634f

// main kernel tiling
#define SPLIT 16       // column splits (blocks cooperating per row-strip)
#define RPB 128        // rows per block (4 waves x 2 strips x 16 rows)
#define CPT 64         // cols per LDS tile
#define LDS_COL 272    // bytes per staged col (256 + 16 pad -> conflict-free)
#define NT ((NROWS / SPLIT) / CPT)   // 8 tiles per block
#define NORM_BLOCKS (NROWS / 4)
#define PACK_BLOCKS 3200   // 100 classes * 128 u64-words / 4 waves

typedef __bf16 bf16x8 __attribute__((ext_vector_type(8)));
typedef float f32x4 __attribute__((ext_vector_type(4)));

__device__ __forceinline__ unsigned int f2bf(float f) {
  union { float f; unsigned int u; } v; v.f = f;
  unsigned int u = v.u;
  return (u + 0x7fffu + ((u >> 16) & 1u)) >> 16;
}
__device__ __forceinline__ float bf2f(unsigned int b) {
  union { unsigned int u; float f; } v; v.u = b << 16;
  return v.f;
}

// Kernel 1 (blocks < NORM_BLOCKS): per-row normalize.
//   xnA = bf16(x/||x|| * log2e/T)  (A operand pre-scaled: e = exp2(acc))
//   xnB = bf16(x/||x||)            (B operand)
//   p = exp2(cos(x,proxy)*log2e/T)  [margin cancels in num/den ratio]
//   e_self = exp2(<xnA_bf16, xnB_bf16>)  (MFMA diagonal, subtracted in loss)
//   mii = negmask[label_i][i]; zero tot/msk/out.
// Kernel 1 (blocks >= NORM_BLOCKS): ballot-pack negmask into u32 bit-words:
//   packed[class*256 + j/32] bit (j&31) = (negmask[class][j] != 0)
__global__ __launch_bounds__(256) void norm_kernel(
    const float* __restrict__ x, const float* __restrict__ pr,
    const float* __restrict__ nm, const int* __restrict__ lb,
    const float* __restrict__ tptr,
    unsigned short* __restrict__ xnA, unsigned short* __restrict__ xnB,
    float* __restrict__ p, float* __restrict__ eself, float* __restrict__ mii,
    float* __restrict__ tot, float* __restrict__ msk,
    unsigned int* __restrict__ packed, float* __restrict__ out)
{
  int wave = threadIdx.x >> 6, lane = threadIdx.x & 63;
  int bx = blockIdx.x;

  if (bx >= NORM_BLOCKS) {
    // ---- mask pack branch ----
    int widx = (bx - NORM_BLOCKS) * 4 + wave;   // 0..12799
    int cls = widx >> 7;                        // 0..99
    int w64 = widx & 127;                       // u64-word within class
    float v = nm[(size_t)cls * NROWS + w64 * 64 + lane];
    unsigned long long b = __ballot(v != 0.0f);
    if (lane == 0) {
      packed[cls * 256 + w64 * 2] = (unsigned int)b;
      packed[cls * 256 + w64 * 2 + 1] = (unsigned int)(b >> 32);
    }
    return;
  }

  int row = bx * 4 + wave;
  float2 xv = ((const float2*)(x + (size_t)row * DD))[lane];
  float2 pv = ((const float2*)(pr + (size_t)row * DD))[lane];
  float sx = xv.x * xv.x + xv.y * xv.y;
  float sp = pv.x * pv.x + pv.y * pv.y;
  float dp = xv.x * pv.x + xv.y * pv.y;
  #pragma unroll
  for (int m = 1; m < 64; m <<= 1) {
    sx += __shfl_xor(sx, m);
    sp += __shfl_xor(sp, m);
    dp += __shfl_xor(dp, m);
  }
  float inx = 1.f / fmaxf(sqrtf(sx), EPS);
  float inp = 1.f / fmaxf(sqrtf(sp), EPS);
  float s1 = LOG2E / tptr[0];

  unsigned int a0 = f2bf(xv.x * inx * s1), a1 = f2bf(xv.y * inx * s1);
  unsigned int b0 = f2bf(xv.x * inx),      b1 = f2bf(xv.y * inx);
  ((unsigned int*)(xnA + (size_t)row * DD))[lane] = a0 | (a1 << 16);
  ((unsigned int*)(xnB + (size_t)row * DD))[lane] = b0 | (b1 << 16);

  // self-sim with the SAME rounded values the MFMA will see
  float ss = bf2f(a0) * bf2f(b0) + bf2f(a1) * bf2f(b1);
  #pragma unroll
  for (int m = 1; m < 64; m <<= 1) ss += __shfl_xor(ss, m);

  if (lane == 0) {
    p[row] = __builtin_amdgcn_exp2f(dp * inx * inp * s1);
    eself[row] = __builtin_amdgcn_exp2f(ss);
    mii[row] = nm[(size_t)lb[row] * NROWS + row];
    tot[row] = 0.f;
    msk[row] = 0.f;
    if (row == 0) out[0] = 0.f;
  }
}

// Kernel 2: fused sim-GEMM + exp + masked/total row-sum accumulation.
// Block = 256 threads = 4 waves; each wave owns 2 strips of 16 rows (RPB=128).
// Grid: (NROWS/RPB, SPLIT). B tiles (CPT=64 cols, 16 KB) staged through
// DOUBLE-BUFFERED LDS (one barrier per tile); coalesced 16B/lane global
// loads; masks bit-packed (uint2 per row per tile, L1-resident).
__global__ __launch_bounds__(256, 4) void main_kernel(
    const unsigned short* __restrict__ xnA_u, const unsigned short* __restrict__ xnB_u,
    const unsigned int* __restrict__ packed, const int* __restrict__ labels,
    float* __restrict__ tot, float* __restrict__ msk)
{
  __shared__ unsigned char lds[2][CPT * LDS_COL];   // 2 x 17408 B
  int tid = threadIdx.x;
  int wave = tid >> 6, lane = tid & 63;
  int q = lane >> 4, c = lane & 15;
  int rb0 = blockIdx.x * RPB + wave * 16;  // strip 0 row base
  int rb1 = rb0 + 64;                      // strip 1 row base

  const bf16x8* xnvA = (const bf16x8*)xnA_u;

  // A fragments (held in registers for the whole column loop)
  // layout: m = lane&15, k = (lane>>4)*8 + j  per 32-wide K step
  bf16x8 a0[4], a1[4];
  {
    const bf16x8* b = xnvA + (size_t)(rb0 + c) * (DD / 8) + q;
    a0[0] = b[0]; a0[1] = b[4]; a0[2] = b[8]; a0[3] = b[12];
  }
  {
    const bf16x8* b = xnvA + (size_t)(rb1 + c) * (DD / 8) + q;
    a1[0] = b[0]; a1[1] = b[4]; a1[2] = b[8]; a1[3] = b[12];
  }

  int jb = blockIdx.y * (NROWS / SPLIT);

  // Epilogue rows for this lane: row_local = q*4 + k, col = s*16 + c
  int r0[4], r1[4];
  unsigned int offP0[4], offP1[4];        // packed-mask word offsets
  #pragma unroll
  for (int k = 0; k < 4; k++) {
    r0[k] = rb0 + q * 4 + k;
    r1[k] = rb1 + q * 4 + k;
    offP0[k] = (unsigned int)labels[r0[k]] * 256u + (unsigned int)(jb >> 5);
    offP1[k] = (unsigned int)labels[r1[k]] * 256u + (unsigned int)(jb >> 5);
  }
  float t0[4] = {0, 0, 0, 0}, m0[4] = {0, 0, 0, 0};
  float t1[4] = {0, 0, 0, 0}, m1[4] = {0, 0, 0, 0};

  // staging: thread t loads/writes 4x 16B: cols scol+16i, chunk schunk
  int scol = tid >> 4, schunk = tid & 15;
  const char* gB = (const char*)xnB_u;
  const char* gbase = gB + (size_t)(jb + scol) * 256 + schunk * 16;
  unsigned int ldsoff = (unsigned int)(scol * LDS_COL + schunk * 16);

  // prefetch + stage tile 0 into buffer 0
  uint4 g0, g1, g2, g3;
  g0 = *(const uint4*)(gbase);
  g1 = *(const uint4*)(gbase + 16 * 256);
  g2 = *(const uint4*)(gbase + 32 * 256);
  g3 = *(const uint4*)(gbase + 48 * 256);
  *(uint4*)(lds[0] + ldsoff)                 = g0;
  *(uint4*)(lds[0] + ldsoff + 16 * LDS_COL)  = g1;
  *(uint4*)(lds[0] + ldsoff + 32 * LDS_COL)  = g2;
  *(uint4*)(lds[0] + ldsoff + 48 * LDS_COL)  = g3;
  __syncthreads();

  for (int t = 0; t < NT; t++) {
    // mask words for this tile (64 cols = 2 u32 per row), L1-resident
    uint2 wc0[4], wc1[4];
    #pragma unroll
    for (int k = 0; k < 4; k++) {
      wc0[k] = *(const uint2*)&packed[offP0[k] + 2 * t];
      wc1[k] = *(const uint2*)&packed[offP1[k] + 2 * t];
    }

    // issue tile t+1 global loads (land during this tile's compute)
    if (t + 1 < NT) {
      const char* gb = gbase + (size_t)(t + 1) * (CPT * 256);
      g0 = *(const uint4*)(gb);
      g1 = *(const uint4*)(gb + 16 * 256);
      g2 = *(const uint4*)(gb + 32 * 256);
      g3 = *(const uint4*)(gb + 48 * 256);
    }

    const unsigned char* buf = lds[t & 1];
    #pragma unroll
    for (int s = 0; s < 4; s++) {
      const bf16x8* bl = (const bf16x8*)(buf + (unsigned)(s * 16 + c) * LDS_COL + q * 16);
      bf16x8 b0 = bl[0], b1 = bl[4], b2 = bl[8], b3 = bl[12];

      f32x4 acc0 = {0, 0, 0, 0};
      f32x4 acc1 = {0, 0, 0, 0};
      acc0 = __builtin_amdgcn_mfma_f32_16x16x32_bf16(a0[0], b0, acc0, 0, 0, 0);
      acc1 = __builtin_amdgcn_mfma_f32_16x16x32_bf16(a1[0], b0, acc1, 0, 0, 0);
      acc0 = __builtin_amdgcn_mfma_f32_16x16x32_bf16(a0[1], b1, acc0, 0, 0, 0);
      acc1 = __builtin_amdgcn_mfma_f32_16x16x32_bf16(a1[1], b1, acc1, 0, 0, 0);
      acc0 = __builtin_amdgcn_mfma_f32_16x16x32_bf16(a0[2], b2, acc0, 0, 0, 0);
      acc1 = __builtin_amdgcn_mfma_f32_16x16x32_bf16(a1[2], b2, acc1, 0, 0, 0);
      acc0 = __builtin_amdgcn_mfma_f32_16x16x32_bf16(a0[3], b3, acc0, 0, 0, 0);
      acc1 = __builtin_amdgcn_mfma_f32_16x16x32_bf16(a1[3], b3, acc1, 0, 0, 0);

      int sh = s * 16 + c;           // bit position within the 64-bit pair
      #pragma unroll
      for (int k = 0; k < 4; k++) {
        unsigned int w = (sh & 32) ? wc0[k].y : wc0[k].x;
        float e = __builtin_amdgcn_exp2f(acc0[k]);
        t0[k] += e;
        m0[k] = fmaf(e, (float)((w >> (sh & 31)) & 1u), m0[k]);
      }
      #pragma unroll
      for (int k = 0; k < 4; k++) {
        unsigned int w = (sh & 32) ? wc1[k].y : wc1[k].x;
        float e = __builtin_amdgcn_exp2f(acc1[k]);
        t1[k] += e;
        m1[k] = fmaf(e, (float)((w >> (sh & 31)) & 1u), m1[k]);
      }
    }

    // stage tile t+1 into the other buffer, then one barrier
    if (t + 1 < NT) {
      unsigned char* nb = (unsigned char*)lds[(t + 1) & 1];
      *(uint4*)(nb + ldsoff)                 = g0;
      *(uint4*)(nb + ldsoff + 16 * LDS_COL)  = g1;
      *(uint4*)(nb + ldsoff + 32 * LDS_COL)  = g2;
      *(uint4*)(nb + ldsoff + 48 * LDS_COL)  = g3;
    }
    __syncthreads();
  }

  // Reduce across the 16 lanes (c) sharing each q group.
  #pragma unroll
  for (int sh = 1; sh < 16; sh <<= 1) {
    #pragma unroll
    for (int k = 0; k < 4; k++) {
      t0[k] += __shfl_xor(t0[k], sh);
      m0[k] += __shfl_xor(m0[k], sh);
      t1[k] += __shfl_xor(t1[k], sh);
      m1[k] += __shfl_xor(m1[k], sh);
    }
  }
  if (c == 0) {
    #pragma unroll
    for (int k = 0; k < 4; k++) {
      atomicAdd(&tot[r0[k]], t0[k]);
      atomicAdd(&msk[r0[k]], m0[k]);
      atomicAdd(&tot[r1[k]], t1[k]);
      atomicAdd(&msk[r1[k]], m1[k]);
    }
  }
}

// Kernel 3: loss = mean(log(p+tot') - log(p+msk')), diagonal subtracted here.
__global__ __launch_bounds__(256) void loss_kernel(
    const float* __restrict__ p, const float* __restrict__ tot,
    const float* __restrict__ msk, const float* __restrict__ eself,
    const float* __restrict__ mii, float* __restrict__ out)
{
  __shared__ float sd[4];
  int r = blockIdx.x * 256 + threadIdx.x;
  float pi = p[r];
  float es = eself[r];
  float t = tot[r] - es;                 // remove diagonal from total sum
  float m = msk[r] - es * mii[r];        // remove diagonal from masked sum
  float v = __builtin_amdgcn_logf(pi + t) - __builtin_amdgcn_logf(pi + m);
  float s = v * (1.0f / (LOG2E * (float)NROWS));
  #pragma unroll
  for (int sh = 1; sh < 64; sh <<= 1) s += __shfl_xor(s, sh);
  int wave = threadIdx.x >> 6, lane = threadIdx.x & 63;
  if (lane == 0) sd[wave] = s;
  __syncthreads();
  if (threadIdx.x == 0) atomicAdd(out, sd[0] + sd[1] + sd[2] + sd[3]);
}

extern "C" void kernel_launch(void* const* d_in, const int* in_sizes, int n_in,
                              void* d_out, int out_size, void* d_ws, size_t ws_size,
                              hipStream_t stream) {
  const float* x  = (const float*)d_in[0];   // inst_embed [N,D]
  const float* pr = (const float*)d_in[1];   // proxy [N,D]
  const float* nm = (const float*)d_in[2];   // negative_mask [100,N]
  const int*   lb = (const int*)d_in[3];     // labels [N]
  const float* tp = (const float*)d_in[4];   // temperature
  // margin (d_in[5]) cancels algebraically in numerator/denominator

  char* ws = (char*)d_ws;
  unsigned short* xnA = (unsigned short*)ws;                        // 2 MB
  unsigned short* xnB = xnA + (size_t)NROWS * DD;                   // 2 MB
  float* p     = (float*)(xnB + (size_t)NROWS * DD);
  float* tot   = p + NROWS;
  float* msk   = tot + NROWS;
  float* eself = msk + NROWS;
  float* miiv  = eself + NROWS;
  unsigned int* packed = (unsigned int*)(miiv + NROWS);             // 102.4 KB
  float* out = (float*)d_out;

  norm_kernel<<<NORM_BLOCKS + PACK_BLOCKS, 256, 0, stream>>>(
      x, pr, nm, lb, tp, xnA, xnB, p, eself, miiv, tot, msk, packed, out);
  main_kernel<<<dim3(NROWS / RPB, SPLIT), 256, 0, stream>>>(xnA, xnB, packed,
                                                            lb, tot, msk);
  loss_kernel<<<NROWS / 256, 256, 0, stream>>>(p, tot, msk, eself, miiv, out);
}

// Round 5
// 102.796 us; speedup vs baseline: 1.2943x; 1.2943x over previous
//
#include <hip/hip_runtime.h>
#include <stdint.h>

#define NROWS 8192
#define DD 128
#define EPS 1e-8f
#define LOG2E 1.4426950408889634f

// main kernel tiling
#define SPLIT 16       // column splits (blocks cooperating per row-strip)
#define RPB 128        // rows per block (4 waves x 2 strips x 16 rows)
#define CPT 32         // cols per LDS tile (keeps staging at 2 uint4/thread — no spill)
#define LDS_COL 272    // bytes per staged col (256+16 pad -> bank group (c+q)%8, conflict-free)
#define NT ((NROWS / SPLIT) / CPT)   // 16 tiles per block
#define NORM_BLOCKS (NROWS / 4)
#define PACK_BLOCKS 3200   // 100 classes * 128 u64-words / 4 waves

typedef __bf16 bf16x8 __attribute__((ext_vector_type(8)));
typedef float f32x4 __attribute__((ext_vector_type(4)));

__device__ __forceinline__ unsigned int f2bf(float f) {
  union { float f; unsigned int u; } v; v.f = f;
  unsigned int u = v.u;
  return (u + 0x7fffu + ((u >> 16) & 1u)) >> 16;
}
__device__ __forceinline__ float bf2f(unsigned int b) {
  union { unsigned int u; float f; } v; v.u = b << 16;
  return v.f;
}

// Kernel 1 (blocks < NORM_BLOCKS): per-row normalize.
//   xnA = bf16(x/||x|| * log2e/T)  (A operand pre-scaled: e = exp2(acc))
//   xnB = bf16(x/||x||)            (B operand)
//   p = exp2(cos(x,proxy)*log2e/T)  [margin cancels in num/den ratio]
//   e_self = exp2(<xnA_bf16, xnB_bf16>)  (MFMA diagonal, subtracted in loss)
//   mii = negmask[label_i][i]; zero tot/msk/out.
// Kernel 1 (blocks >= NORM_BLOCKS): ballot-pack negmask into u32 bit-words:
//   packed[class*256 + j/32] bit (j&31) = (negmask[class][j] != 0)
__global__ __launch_bounds__(256) void norm_kernel(
    const float* __restrict__ x, const float* __restrict__ pr,
    const float* __restrict__ nm, const int* __restrict__ lb,
    const float* __restrict__ tptr,
    unsigned short* __restrict__ xnA, unsigned short* __restrict__ xnB,
    float* __restrict__ p, float* __restrict__ eself, float* __restrict__ mii,
    float* __restrict__ tot, float* __restrict__ msk,
    unsigned int* __restrict__ packed, float* __restrict__ out)
{
  int wave = threadIdx.x >> 6, lane = threadIdx.x & 63;
  int bx = blockIdx.x;

  if (bx >= NORM_BLOCKS) {
    // ---- mask pack branch ----
    int widx = (bx - NORM_BLOCKS) * 4 + wave;   // 0..12799
    int cls = widx >> 7;                        // 0..99
    int w64 = widx & 127;                       // u64-word within class
    float v = nm[(size_t)cls * NROWS + w64 * 64 + lane];
    unsigned long long b = __ballot(v != 0.0f);
    if (lane == 0) {
      packed[cls * 256 + w64 * 2] = (unsigned int)b;
      packed[cls * 256 + w64 * 2 + 1] = (unsigned int)(b >> 32);
    }
    return;
  }

  int row = bx * 4 + wave;
  float2 xv = ((const float2*)(x + (size_t)row * DD))[lane];
  float2 pv = ((const float2*)(pr + (size_t)row * DD))[lane];
  float sx = xv.x * xv.x + xv.y * xv.y;
  float sp = pv.x * pv.x + pv.y * pv.y;
  float dp = xv.x * pv.x + xv.y * pv.y;
  #pragma unroll
  for (int m = 1; m < 64; m <<= 1) {
    sx += __shfl_xor(sx, m);
    sp += __shfl_xor(sp, m);
    dp += __shfl_xor(dp, m);
  }
  float inx = 1.f / fmaxf(sqrtf(sx), EPS);
  float inp = 1.f / fmaxf(sqrtf(sp), EPS);
  float s1 = LOG2E / tptr[0];

  unsigned int a0 = f2bf(xv.x * inx * s1), a1 = f2bf(xv.y * inx * s1);
  unsigned int b0 = f2bf(xv.x * inx),      b1 = f2bf(xv.y * inx);
  ((unsigned int*)(xnA + (size_t)row * DD))[lane] = a0 | (a1 << 16);
  ((unsigned int*)(xnB + (size_t)row * DD))[lane] = b0 | (b1 << 16);

  // self-sim with the SAME rounded values the MFMA will see
  float ss = bf2f(a0) * bf2f(b0) + bf2f(a1) * bf2f(b1);
  #pragma unroll
  for (int m = 1; m < 64; m <<= 1) ss += __shfl_xor(ss, m);

  if (lane == 0) {
    p[row] = __builtin_amdgcn_exp2f(dp * inx * inp * s1);
    eself[row] = __builtin_amdgcn_exp2f(ss);
    mii[row] = nm[(size_t)lb[row] * NROWS + row];
    tot[row] = 0.f;
    msk[row] = 0.f;
    if (row == 0) out[0] = 0.f;
  }
}

// Kernel 2: fused sim-GEMM + exp + masked/total row-sum accumulation.
// Block = 256 threads = 4 waves; each wave owns 2 strips of 16 rows (RPB=128).
// Grid: (NROWS/RPB, SPLIT). B tiles (CPT=32 cols, 8.5 KB) staged through
// DOUBLE-BUFFERED LDS with ONE barrier per tile. Staging is 2 uint4/thread
// (R3-proven, no spill). Masks bit-packed u32 per 32 cols.
__global__ __launch_bounds__(256, 4) void main_kernel(
    const unsigned short* __restrict__ xnA_u, const unsigned short* __restrict__ xnB_u,
    const unsigned int* __restrict__ packed, const int* __restrict__ labels,
    float* __restrict__ tot, float* __restrict__ msk)
{
  __shared__ unsigned char lds[2][CPT * LDS_COL];   // 2 x 8704 B
  int tid = threadIdx.x;
  int wave = tid >> 6, lane = tid & 63;
  int q = lane >> 4, c = lane & 15;
  int rb0 = blockIdx.x * RPB + wave * 16;  // strip 0 row base
  int rb1 = rb0 + 64;                      // strip 1 row base

  const bf16x8* xnvA = (const bf16x8*)xnA_u;

  // A fragments (held in registers for the whole column loop)
  // layout: m = lane&15, k = (lane>>4)*8 + j  per 32-wide K step
  bf16x8 a0[4], a1[4];
  {
    const bf16x8* b = xnvA + (size_t)(rb0 + c) * (DD / 8) + q;
    a0[0] = b[0]; a0[1] = b[4]; a0[2] = b[8]; a0[3] = b[12];
  }
  {
    const bf16x8* b = xnvA + (size_t)(rb1 + c) * (DD / 8) + q;
    a1[0] = b[0]; a1[1] = b[4]; a1[2] = b[8]; a1[3] = b[12];
  }

  int jb = blockIdx.y * (NROWS / SPLIT);

  // Epilogue rows for this lane: row_local = q*4 + k, col = s*16 + c
  int r0[4], r1[4];
  unsigned int offP0[4], offP1[4];        // packed-mask word offsets
  #pragma unroll
  for (int k = 0; k < 4; k++) {
    r0[k] = rb0 + q * 4 + k;
    r1[k] = rb1 + q * 4 + k;
    offP0[k] = (unsigned int)labels[r0[k]] * 256u + (unsigned int)(jb >> 5);
    offP1[k] = (unsigned int)labels[r1[k]] * 256u + (unsigned int)(jb >> 5);
  }
  float t0[4] = {0, 0, 0, 0}, m0[4] = {0, 0, 0, 0};
  float t1[4] = {0, 0, 0, 0}, m1[4] = {0, 0, 0, 0};

  // staging: thread t loads/writes 2x 16B: cols scol, scol+16, chunk schunk
  int scol = tid >> 4, schunk = tid & 15;
  const char* gB = (const char*)xnB_u;
  const char* gbase = gB + (size_t)(jb + scol) * 256 + schunk * 16;
  unsigned int ldsoff = (unsigned int)(scol * LDS_COL + schunk * 16);

  // prefetch + stage tile 0 into buffer 0
  uint4 g0 = *(const uint4*)(gbase);
  uint4 g1 = *(const uint4*)(gbase + 16 * 256);
  unsigned int wn0[4], wn1[4];
  #pragma unroll
  for (int k = 0; k < 4; k++) {
    wn0[k] = packed[offP0[k]];
    wn1[k] = packed[offP1[k]];
  }
  *(uint4*)(lds[0] + ldsoff)                = g0;
  *(uint4*)(lds[0] + ldsoff + 16 * LDS_COL) = g1;
  __syncthreads();

  for (int t = 0; t < NT; t++) {
    unsigned int wc0[4], wc1[4];
    #pragma unroll
    for (int k = 0; k < 4; k++) { wc0[k] = wn0[k]; wc1[k] = wn1[k]; }

    // issue tile t+1 loads (land during this tile's compute)
    if (t + 1 < NT) {
      const char* gb = gbase + (size_t)(t + 1) * (CPT * 256);
      g0 = *(const uint4*)(gb);
      g1 = *(const uint4*)(gb + 16 * 256);
      #pragma unroll
      for (int k = 0; k < 4; k++) {
        wn0[k] = packed[offP0[k] + t + 1];
        wn1[k] = packed[offP1[k] + t + 1];
      }
    }

    const unsigned char* buf = lds[t & 1];
    #pragma unroll
    for (int s = 0; s < 2; s++) {
      const bf16x8* bl = (const bf16x8*)(buf + (unsigned)(s * 16 + c) * LDS_COL + q * 16);
      bf16x8 b0 = bl[0], b1 = bl[4], b2 = bl[8], b3 = bl[12];

      f32x4 acc0 = {0, 0, 0, 0};
      f32x4 acc1 = {0, 0, 0, 0};
      acc0 = __builtin_amdgcn_mfma_f32_16x16x32_bf16(a0[0], b0, acc0, 0, 0, 0);
      acc1 = __builtin_amdgcn_mfma_f32_16x16x32_bf16(a1[0], b0, acc1, 0, 0, 0);
      acc0 = __builtin_amdgcn_mfma_f32_16x16x32_bf16(a0[1], b1, acc0, 0, 0, 0);
      acc1 = __builtin_amdgcn_mfma_f32_16x16x32_bf16(a1[1], b1, acc1, 0, 0, 0);
      acc0 = __builtin_amdgcn_mfma_f32_16x16x32_bf16(a0[2], b2, acc0, 0, 0, 0);
      acc1 = __builtin_amdgcn_mfma_f32_16x16x32_bf16(a1[2], b2, acc1, 0, 0, 0);
      acc0 = __builtin_amdgcn_mfma_f32_16x16x32_bf16(a0[3], b3, acc0, 0, 0, 0);
      acc1 = __builtin_amdgcn_mfma_f32_16x16x32_bf16(a1[3], b3, acc1, 0, 0, 0);

      int pos = s * 16 + c;   // bit position in the packed u32 word
      #pragma unroll
      for (int k = 0; k < 4; k++) {
        float e = __builtin_amdgcn_exp2f(acc0[k]);
        t0[k] += e;
        m0[k] = fmaf(e, (float)((wc0[k] >> pos) & 1u), m0[k]);
      }
      #pragma unroll
      for (int k = 0; k < 4; k++) {
        float e = __builtin_amdgcn_exp2f(acc1[k]);
        t1[k] += e;
        m1[k] = fmaf(e, (float)((wc1[k] >> pos) & 1u), m1[k]);
      }
    }

    // stage tile t+1 into the other buffer (waits on prefetch), one barrier
    if (t + 1 < NT) {
      unsigned char* nb = (unsigned char*)lds[(t + 1) & 1];
      *(uint4*)(nb + ldsoff)                = g0;
      *(uint4*)(nb + ldsoff + 16 * LDS_COL) = g1;
    }
    __syncthreads();
  }

  // Reduce across the 16 lanes (c) sharing each q group.
  #pragma unroll
  for (int sh = 1; sh < 16; sh <<= 1) {
    #pragma unroll
    for (int k = 0; k < 4; k++) {
      t0[k] += __shfl_xor(t0[k], sh);
      m0[k] += __shfl_xor(m0[k], sh);
      t1[k] += __shfl_xor(t1[k], sh);
      m1[k] += __shfl_xor(m1[k], sh);
    }
  }
  if (c == 0) {
    #pragma unroll
    for (int k = 0; k < 4; k++) {
      atomicAdd(&tot[r0[k]], t0[k]);
      atomicAdd(&msk[r0[k]], m0[k]);
      atomicAdd(&tot[r1[k]], t1[k]);
      atomicAdd(&msk[r1[k]], m1[k]);
    }
  }
}

// Kernel 3: loss = mean(log(p+tot') - log(p+msk')), diagonal subtracted here.
__global__ __launch_bounds__(256) void loss_kernel(
    const float* __restrict__ p, const float* __restrict__ tot,
    const float* __restrict__ msk, const float* __restrict__ eself,
    const float* __restrict__ mii, float* __restrict__ out)
{
  __shared__ float sd[4];
  int r = blockIdx.x * 256 + threadIdx.x;
  float pi = p[r];
  float es = eself[r];
  float t = tot[r] - es;                 // remove diagonal from total sum
  float m = msk[r] - es * mii[r];        // remove diagonal from masked sum
  float v = __builtin_amdgcn_logf(pi + t) - __builtin_amdgcn_logf(pi + m);
  float s = v * (1.0f / (LOG2E * (float)NROWS));
  #pragma unroll
  for (int sh = 1; sh < 64; sh <<= 1) s += __shfl_xor(s, sh);
  int wave = threadIdx.x >> 6, lane = threadIdx.x & 63;
  if (lane == 0) sd[wave] = s;
  __syncthreads();
  if (threadIdx.x == 0) atomicAdd(out, sd[0] + sd[1] + sd[2] + sd[3]);
}

extern "C" void kernel_launch(void* const* d_in, const int* in_sizes, int n_in,
                              void* d_out, int out_size, void* d_ws, size_t ws_size,
                              hipStream_t stream) {
  const float* x  = (const float*)d_in[0];   // inst_embed [N,D]
  const float* pr = (const float*)d_in[1];   // proxy [N,D]
  const float* nm = (const float*)d_in[2];   // negative_mask [100,N]
  const int*   lb = (const int*)d_in[3];     // labels [N]
  const float* tp = (const float*)d_in[4];   // temperature
  // margin (d_in[5]) cancels algebraically in numerator/denominator

  char* ws = (char*)d_ws;
  unsigned short* xnA = (unsigned short*)ws;                        // 2 MB
  unsigned short* xnB = xnA + (size_t)NROWS * DD;                   // 2 MB
  float* p     = (float*)(xnB + (size_t)NROWS * DD);
  float* tot   = p + NROWS;
  float* msk   = tot + NROWS;
  float* eself = msk + NROWS;
  float* miiv  = eself + NROWS;
  unsigned int* packed = (unsigned int*)(miiv + NROWS);             // 102.4 KB
  float* out = (float*)d_out;

  norm_kernel<<<NORM_BLOCKS + PACK_BLOCKS, 256, 0, stream>>>(
      x, pr, nm, lb, tp, xnA, xnB, p, eself, miiv, tot, msk, packed, out);
  main_kernel<<<dim3(NROWS / RPB, SPLIT), 256, 0, stream>>>(xnA, xnB, packed,
                                                            lb, tot, msk);
  loss_kernel<<<NROWS / 256, 256, 0, stream>>>(p, tot, msk, eself, miiv, out);
}